// Round 4
// baseline (1674.373 us; speedup 1.0000x reference)
//
#include <hip/hip_runtime.h>

#define N_NODES 100000
#define N_EDGES 1200000
#define R_REL 3
#define RN (R_REL * N_NODES)   // 300000
#define RE (R_REL * N_EDGES)   // 3600000

typedef unsigned int uint;

__device__ __forceinline__ float bcast(float v, int l) {
  return __int_as_float(__builtin_amdgcn_readlane(__float_as_int(v), l));
}
__device__ __forceinline__ int rfl(int v) { return __builtin_amdgcn_readfirstlane(v); }
__device__ __forceinline__ uint bf16r(float x) {  // round-to-nearest-even bf16
  uint u = __float_as_uint(x);
  return (u + 0x7fffu + ((u >> 16) & 1u)) >> 16;
}
__device__ __forceinline__ float lo16(uint u) { return __uint_as_float(u << 16); }
__device__ __forceinline__ float hi16(uint u) { return __uint_as_float(u & 0xffff0000u); }

// ---------------- CSR build ----------------
__global__ void k_count(const int* __restrict__ dst, int* __restrict__ deg,
                        int* __restrict__ rank) {
  int i = blockIdx.x * 256 + threadIdx.x;
  if (i < RE) {
    int r = i / N_EDGES;
    rank[i] = atomicAdd(&deg[r * N_NODES + dst[i]], 1);
  }
}

__global__ void k_scan1(const int* __restrict__ deg, int* __restrict__ P,
                        int* __restrict__ bsums) {
  __shared__ int sd[256];
  int t = threadIdx.x;
  int base = blockIdx.x * 2048 + t * 8;
  int v[8];
  int tot = 0;
#pragma unroll
  for (int q = 0; q < 8; q++) {
    v[q] = (base + q < RN) ? deg[base + q] : 0;
    tot += v[q];
  }
  sd[t] = tot;
  __syncthreads();
  for (int off = 1; off < 256; off <<= 1) {
    int x = (t >= off) ? sd[t - off] : 0;
    __syncthreads();
    sd[t] += x;
    __syncthreads();
  }
  int run = sd[t] - tot;
#pragma unroll
  for (int q = 0; q < 8; q++) {
    if (base + q < RN) P[base + q] = run;
    run += v[q];
  }
  if (t == 255) bsums[blockIdx.x] = sd[255];
}

__global__ void k_scan2(const int* __restrict__ bsums, int* __restrict__ boffs, int nb) {
  __shared__ int sd[256];
  int t = threadIdx.x;
  int v = (t < nb) ? bsums[t] : 0;
  sd[t] = v;
  __syncthreads();
  for (int off = 1; off < 256; off <<= 1) {
    int x = (t >= off) ? sd[t - off] : 0;
    __syncthreads();
    sd[t] += x;
    __syncthreads();
  }
  if (t < nb) boffs[t] = sd[t] - v;
}

__global__ void k_scan3(int* __restrict__ P, const int* __restrict__ boffs) {
  int i = blockIdx.x * 256 + threadIdx.x;
  if (i < RN) P[i] += boffs[i >> 11];
}

__global__ void k_scatter(const int* __restrict__ src, const int* __restrict__ dst,
                          const int* __restrict__ rank, const int* __restrict__ P,
                          int* __restrict__ ssrc) {
  int i = blockIdx.x * 256 + threadIdx.x;
  if (i < RE) {
    int r = i / N_EDGES;
    ssrc[P[r * N_NODES + dst[i]] + rank[i]] = src[i];
  }
  if (i < 8) ssrc[RE + i] = 0;  // prefetch pad
}

// ---------------- node transforms ----------------
// pck[(r*N+n)*64 + c] = (bf16(hp_r[n][c])<<16) | bf16(es[n][c])   (256B rows, aligned)
// asrc[(r*N+n)*4 + head], adst[(r*N+n)*4 + head] : fp32
__global__ __launch_bounds__(256) void k_node(
    const float* __restrict__ h, const float* __restrict__ d_w,
    const float* __restrict__ d_b, const float* __restrict__ w_w,
    const float* __restrict__ w_b, const float* __restrict__ atten_w,
    const float* __restrict__ atten_b, uint* __restrict__ pck,
    float* __restrict__ asrc, float* __restrict__ adst) {
  __shared__ float sW[4 * 4096];  // 64 KB: d_w, w_w[0..2], layout [m][k*64+c]
  int tid = threadIdx.x;
  for (int idx = tid; idx < 4096; idx += 256) {
    sW[idx] = d_w[idx];
    sW[4096 + idx] = w_w[idx];
    sW[8192 + idx] = w_w[4096 + idx];
    sW[12288 + idx] = w_w[8192 + idx];
  }
  __syncthreads();
  int lane = tid & 63, wid = tid >> 6;
  int wave = blockIdx.x * 4 + wid, nw = gridDim.x * 4;
  int k16 = lane & 15, hgrp = lane >> 4;
  float dbv = d_b[lane];
  float wbv0 = w_b[lane], wbv1 = w_b[64 + lane], wbv2 = w_b[128 + lane];
  float wa0[3], wa1[3], wa2[3], ab[3];
#pragma unroll
  for (int r = 0; r < 3; r++) {
    wa0[r] = atten_w[r * 48 + k16];
    wa1[r] = atten_w[r * 48 + 16 + k16];
    wa2[r] = atten_w[r * 48 + 32 + k16];
    ab[r] = atten_b[r];
  }
  for (int g = wave; g < N_NODES / 8; g += nw) {
    int n0 = g * 8;
    float hr[8];
#pragma unroll
    for (int i = 0; i < 8; i++) hr[i] = h[(n0 + i) * 64 + lane];
    float acc[8][4];
#pragma unroll
    for (int i = 0; i < 8; i++) {
      acc[i][0] = dbv; acc[i][1] = wbv0; acc[i][2] = wbv1; acc[i][3] = wbv2;
    }
#pragma unroll 4
    for (int k = 0; k < 64; k++) {
      float w0 = sW[k * 64 + lane];
      float w1 = sW[4096 + k * 64 + lane];
      float w2 = sW[8192 + k * 64 + lane];
      float w3 = sW[12288 + k * 64 + lane];
#pragma unroll
      for (int i = 0; i < 8; i++) {
        float a = bcast(hr[i], k);
        acc[i][0] += a * w0; acc[i][1] += a * w1;
        acc[i][2] += a * w2; acc[i][3] += a * w3;
      }
    }
#pragma unroll
    for (int i = 0; i < 8; i++) {
      int n = n0 + i;
      float esv = tanhf(2.f * acc[i][0]);
      uint esb = bf16r(esv);
#pragma unroll
      for (int r = 0; r < 3; r++) {
        float hpv = acc[i][1 + r];
        int idxrn = r * N_NODES + n;
        pck[(size_t)idxrn * 64 + lane] = (bf16r(hpv) << 16) | esb;
        float cs = hpv * wa0[r] + esv * wa2[r];
        float cd = hpv * wa1[r];
#pragma unroll
        for (int m = 1; m < 16; m <<= 1) {
          cs += __shfl_xor(cs, m);
          cd += __shfl_xor(cd, m);
        }
        if (k16 == 0) {
          asrc[(size_t)idxrn * 4 + hgrp] = cs + ab[r];
          adst[(size_t)idxrn * 4 + hgrp] = cd;
        }
      }
    }
  }
}

// ---------------- per-edge normalized softmax weights ----------------
// uex[p*4 + head] = exp(lrelu(asrc[s]+adst[t])) / sum_over_segment
// one wave per (r,t) segment; lane = edge_off*4 + head (16 edges / pass)
__global__ __launch_bounds__(512) void k_edge(
    const float* __restrict__ asrc, const float* __restrict__ adst,
    const int* __restrict__ P, const int* __restrict__ ssrc,
    float* __restrict__ uex) {
  int tid = threadIdx.x;
  int lane = tid & 63, wid = tid >> 6;
  int idxrn = blockIdx.x * 8 + wid;
  if (idxrn >= RN) return;
  int beg = P[idxrn];
  int end = (idxrn + 1 < RN) ? P[idxrn + 1] : RE;
  if (beg == end) return;
  int r = idxrn / N_NODES;
  int rbase4 = r * N_NODES * 4;
  int head = lane & 3, eo = lane >> 2;
  float adh = adst[(size_t)idxrn * 4 + head];
  int nE = end - beg;
  if (nE <= 16) {  // fast path (~90% of segments)
    int p = beg + eo;
    float ex = 0.f;
    if (eo < nE) {
      int s = ssrc[p];
      float a = asrc[rbase4 + s * 4 + head] + adh;
      a = a >= 0.f ? a : 0.01f * a;
      ex = __expf(a);
    }
    float dsum = ex;
#pragma unroll
    for (int m = 4; m < 64; m <<= 1) dsum += __shfl_xor(dsum, m);
    float rinv = 1.f / fmaxf(dsum, 1e-20f);
    if (eo < nE) uex[(size_t)p * 4 + head] = ex * rinv;
  } else {  // general: two passes (second gather is cache-hot)
    float dsum = 0.f;
    for (int p0 = beg; p0 < end; p0 += 16) {
      int p = p0 + eo;
      if (p < end) {
        int s = ssrc[p];
        float a = asrc[rbase4 + s * 4 + head] + adh;
        a = a >= 0.f ? a : 0.01f * a;
        dsum += __expf(a);
      }
    }
#pragma unroll
    for (int m = 4; m < 64; m <<= 1) dsum += __shfl_xor(dsum, m);
    float rinv = 1.f / fmaxf(dsum, 1e-20f);
    for (int p0 = beg; p0 < end; p0 += 16) {
      int p = p0 + eo;
      if (p < end) {
        int s = ssrc[p];
        float a = asrc[rbase4 + s * 4 + head] + adh;
        a = a >= 0.f ? a : 0.01f * a;
        uex[(size_t)p * 4 + head] = __expf(a) * rinv;
      }
    }
  }
}

// ---------------- fused: per-dst weighted aggregate + gate + final linear ----------------
__global__ __launch_bounds__(512, 8) void k_fused(
    const uint* __restrict__ pck, const float* __restrict__ uex,
    const int* __restrict__ P, const int* __restrict__ ssrc,
    const float* __restrict__ beta, const float* __restrict__ lin_w,
    const float* __restrict__ lin_b, float* __restrict__ out) {
  // lin_w transposed + bf16-packed: sU[c*98 + jp] = (bf16(w[2jp+1][c])<<16)|bf16(w[2jp][c])
  __shared__ uint sU[64 * 98];  // 25088 B
  int tid = threadIdx.x;
  for (int idx = tid; idx < 96 * 64; idx += 512) {
    int c = idx & 63, jp = idx >> 6;
    float w0 = lin_w[(2 * jp) * 64 + c];
    float w1 = lin_w[(2 * jp + 1) * 64 + c];
    sU[c * 98 + jp] = (bf16r(w1) << 16) | bf16r(w0);
  }
  __syncthreads();
  int lane = tid & 63, wid = tid >> 6;
  int g = blockIdx.x * 8 + wid;  // 4 nodes per wave
  int hgrp = lane >> 4;
  float y0 = lin_b[lane];
  float y[4] = {y0, y0, y0, y0};
#pragma unroll
  for (int r = 0; r < 3; r++) {
    float hr[4];
    float b0 = beta[r * 128 + lane], b1 = beta[r * 128 + 64 + lane];
    int rbase = r * N_NODES;
    for (int i = 0; i < 4; i++) {
      int n = g * 4 + i;
      int idxrn = rbase + n;
      int beg = P[idxrn];
      int end = (idxrn + 1 < RN) ? P[idxrn + 1] : RE;
      float hpself = hi16(pck[(size_t)idxrn * 64 + lane]);  // early issue
      float oacc = 0.f, eacc = 0.f;
      // depth-3 pipeline; prefetch runs into next (contiguous) segment harmlessly
      int sA = rfl(__builtin_nontemporal_load(&ssrc[beg]));
      int sB = rfl(__builtin_nontemporal_load(&ssrc[beg + 1]));
      int sC = rfl(__builtin_nontemporal_load(&ssrc[beg + 2]));
      uint pvA = pck[((size_t)(rbase + sA) << 6) + lane];
      float wA = __builtin_nontemporal_load(&uex[((size_t)beg << 2) + hgrp]);
      uint pvB = pck[((size_t)(rbase + sB) << 6) + lane];
      float wB = __builtin_nontemporal_load(&uex[((size_t)(beg + 1) << 2) + hgrp]);
      uint pvC = pck[((size_t)(rbase + sC) << 6) + lane];
      float wC = __builtin_nontemporal_load(&uex[((size_t)(beg + 2) << 2) + hgrp]);
      for (int e = beg; e < end; ++e) {
        uint pv = pvA; float w = wA;
        pvA = pvB; wA = wB;
        pvB = pvC; wB = wC;
        int sD = rfl(__builtin_nontemporal_load(&ssrc[e + 3]));
        pvC = pck[((size_t)(rbase + sD) << 6) + lane];
        wC = __builtin_nontemporal_load(&uex[((size_t)(e + 3) << 2) + hgrp]);
        oacc += w * hi16(pv);
        eacc += lo16(pv);
      }
      float em = eacc / fmaxf((float)(end - beg), 1.f);
      float gc = em * b0 + oacc * b1;
#pragma unroll
      for (int m = 1; m < 64; m <<= 1) gc += __shfl_xor(gc, m);
      float gt = 1.f / (1.f + __expf(-gc));
      hr[i] = gt * oacc + (1.f - gt) * hpself;
    }
    const uint* wrow = &sU[lane * 98 + r * 32];
#pragma unroll
    for (int jp = 0; jp < 32; jp += 2) {
      uint2 wv = *reinterpret_cast<const uint2*>(wrow + jp);
      float w0 = lo16(wv.x), w1 = hi16(wv.x), w2 = lo16(wv.y), w3 = hi16(wv.y);
#pragma unroll
      for (int i = 0; i < 4; i++) {
        y[i] += bcast(hr[i], 2 * jp) * w0 + bcast(hr[i], 2 * jp + 1) * w1 +
                bcast(hr[i], 2 * jp + 2) * w2 + bcast(hr[i], 2 * jp + 3) * w3;
      }
    }
  }
#pragma unroll
  for (int i = 0; i < 4; i++) out[(size_t)(g * 4 + i) * 64 + lane] = y[i];
}

extern "C" void kernel_launch(void* const* d_in, const int* in_sizes, int n_in,
                              void* d_out, int out_size, void* d_ws, size_t ws_size,
                              hipStream_t stream) {
  const float* h = (const float*)d_in[0];
  const int* src = (const int*)d_in[1];
  const int* dst = (const int*)d_in[2];
  const float* d_w = (const float*)d_in[3];
  const float* d_b = (const float*)d_in[4];
  const float* w_w = (const float*)d_in[5];
  const float* w_b = (const float*)d_in[6];
  const float* atten_w = (const float*)d_in[7];
  const float* atten_b = (const float*)d_in[8];
  const float* beta = (const float*)d_in[9];
  const float* lin_w = (const float*)d_in[10];
  const float* lin_b = (const float*)d_in[11];
  float* out = (float*)d_out;

  uint* pck = (uint*)d_ws;                        // RN*64 uints (76.8 MB)
  float* asrc = (float*)(pck + (size_t)RN * 64);  // RN*4
  float* adst = asrc + (size_t)RN * 4;            // RN*4
  int* deg = (int*)(adst + (size_t)RN * 4);       // RN
  int* P = deg + RN;                              // RN
  int* bsums = P + RN;                            // 256
  int* boffs = bsums + 256;                       // 256
  int* rank = boffs + 256;                        // RE
  int* ssrc = rank + RE;                          // RE + 8
  float* uex = (float*)(ssrc + RE + 8);           // RE*4 + 16 (57.6 MB)

  int nb = (RN + 2047) / 2048;
  hipMemsetAsync(deg, 0, RN * sizeof(int), stream);
  k_count<<<(RE + 255) / 256, 256, 0, stream>>>(dst, deg, rank);
  k_scan1<<<nb, 256, 0, stream>>>(deg, P, bsums);
  k_scan2<<<1, 256, 0, stream>>>(bsums, boffs, nb);
  k_scan3<<<(RN + 255) / 256, 256, 0, stream>>>(P, boffs);
  k_scatter<<<(RE + 255) / 256, 256, 0, stream>>>(src, dst, rank, P, ssrc);
  k_node<<<1024, 256, 0, stream>>>(h, d_w, d_b, w_w, w_b, atten_w, atten_b, pck,
                                   asrc, adst);
  k_edge<<<(RN + 7) / 8, 512, 0, stream>>>(asrc, adst, P, ssrc, uex);
  k_fused<<<N_NODES / 32, 512, 0, stream>>>(pck, uex, P, ssrc, beta, lin_w, lin_b, out);
}

// Round 6
// 1614.075 us; speedup vs baseline: 1.0374x; 1.0374x over previous
//
#include <hip/hip_runtime.h>

#define N_NODES 100000
#define N_EDGES 1200000
#define R_REL 3
#define RN (R_REL * N_NODES)   // 300000
#define RE (R_REL * N_EDGES)   // 3600000

typedef unsigned int uint;

__device__ __forceinline__ float bcast(float v, int l) {
  return __int_as_float(__builtin_amdgcn_readlane(__float_as_int(v), l));
}
__device__ __forceinline__ uint bf16r(float x) {  // round-to-nearest-even bf16
  uint u = __float_as_uint(x);
  return (u + 0x7fffu + ((u >> 16) & 1u)) >> 16;
}
__device__ __forceinline__ float lo16(uint u) { return __uint_as_float(u << 16); }
__device__ __forceinline__ float hi16(uint u) { return __uint_as_float(u & 0xffff0000u); }

// ---------------- CSR build ----------------
__global__ void k_zero(int* __restrict__ p, int n) {
  int i = blockIdx.x * 256 + threadIdx.x;
  if (i < n) p[i] = 0;
}

__global__ void k_count(const int* __restrict__ dst, int* __restrict__ deg,
                        int* __restrict__ rank) {
  int i = blockIdx.x * 256 + threadIdx.x;
  if (i < RE) {
    int r = i / N_EDGES;
    rank[i] = atomicAdd(&deg[r * N_NODES + dst[i]], 1);
  }
}

__global__ void k_scan1(const int* __restrict__ deg, int* __restrict__ P,
                        int* __restrict__ bsums) {
  __shared__ int sd[256];
  int t = threadIdx.x;
  int base = blockIdx.x * 2048 + t * 8;
  int v[8];
  int tot = 0;
#pragma unroll
  for (int q = 0; q < 8; q++) {
    v[q] = (base + q < RN) ? deg[base + q] : 0;
    tot += v[q];
  }
  sd[t] = tot;
  __syncthreads();
  for (int off = 1; off < 256; off <<= 1) {
    int x = (t >= off) ? sd[t - off] : 0;
    __syncthreads();
    sd[t] += x;
    __syncthreads();
  }
  int run = sd[t] - tot;
#pragma unroll
  for (int q = 0; q < 8; q++) {
    if (base + q < RN) P[base + q] = run;
    run += v[q];
  }
  if (t == 255) bsums[blockIdx.x] = sd[255];
}

__global__ void k_scan2(const int* __restrict__ bsums, int* __restrict__ boffs, int nb) {
  __shared__ int sd[256];
  int t = threadIdx.x;
  int v = (t < nb) ? bsums[t] : 0;
  sd[t] = v;
  __syncthreads();
  for (int off = 1; off < 256; off <<= 1) {
    int x = (t >= off) ? sd[t - off] : 0;
    __syncthreads();
    sd[t] += x;
    __syncthreads();
  }
  if (t < nb) boffs[t] = sd[t] - v;
}

__global__ void k_scan3(int* __restrict__ P, const int* __restrict__ boffs) {
  int i = blockIdx.x * 256 + threadIdx.x;
  if (i < RN) P[i] += boffs[i >> 11];
}

__global__ void k_scatter(const int* __restrict__ src, const int* __restrict__ dst,
                          const int* __restrict__ rank, const int* __restrict__ P,
                          int* __restrict__ ssrc) {
  int i = blockIdx.x * 256 + threadIdx.x;
  if (i < RE) {
    int r = i / N_EDGES;
    ssrc[P[r * N_NODES + dst[i]] + rank[i]] = src[i];
  }
  if (i < 16) ssrc[RE + i] = 0;  // pad (not strictly needed; insurance)
}

// ---------------- node transforms ----------------
// pck[(r*N+n)*32 + j] = (bf16(hp[2j+1])<<16) | bf16(hp[2j])   (128B rows, 1 line)
// asrc/adst[(r*N+n)*4 + head] : fp32 ; q[(r*N+n)] = dot(es[n], beta_r[0:64]) fp32
__global__ __launch_bounds__(256) void k_node(
    const float* __restrict__ h, const float* __restrict__ d_w,
    const float* __restrict__ d_b, const float* __restrict__ w_w,
    const float* __restrict__ w_b, const float* __restrict__ atten_w,
    const float* __restrict__ atten_b, const float* __restrict__ beta,
    uint* __restrict__ pck, float* __restrict__ asrc, float* __restrict__ adst,
    float* __restrict__ q) {
  __shared__ float sW[4 * 4096];  // 64 KB: d_w, w_w[0..2], layout [m][k*64+c]
  int tid = threadIdx.x;
  for (int idx = tid; idx < 4096; idx += 256) {
    sW[idx] = d_w[idx];
    sW[4096 + idx] = w_w[idx];
    sW[8192 + idx] = w_w[4096 + idx];
    sW[12288 + idx] = w_w[8192 + idx];
  }
  __syncthreads();
  int lane = tid & 63, wid = tid >> 6;
  int wave = blockIdx.x * 4 + wid, nw = gridDim.x * 4;
  int k16 = lane & 15, hgrp = lane >> 4;
  float dbv = d_b[lane];
  float wbv0 = w_b[lane], wbv1 = w_b[64 + lane], wbv2 = w_b[128 + lane];
  float wa0[3], wa1[3], wa2[3], ab[3], bq[3];
#pragma unroll
  for (int r = 0; r < 3; r++) {
    wa0[r] = atten_w[r * 48 + k16];
    wa1[r] = atten_w[r * 48 + 16 + k16];
    wa2[r] = atten_w[r * 48 + 32 + k16];
    ab[r] = atten_b[r];
    bq[r] = beta[r * 128 + lane];
  }
  for (int g = wave; g < N_NODES / 8; g += nw) {
    int n0 = g * 8;
    float hr[8];
#pragma unroll
    for (int i = 0; i < 8; i++) hr[i] = h[(n0 + i) * 64 + lane];
    float acc[8][4];
#pragma unroll
    for (int i = 0; i < 8; i++) {
      acc[i][0] = dbv; acc[i][1] = wbv0; acc[i][2] = wbv1; acc[i][3] = wbv2;
    }
#pragma unroll 4
    for (int k = 0; k < 64; k++) {
      float w0 = sW[k * 64 + lane];
      float w1 = sW[4096 + k * 64 + lane];
      float w2 = sW[8192 + k * 64 + lane];
      float w3 = sW[12288 + k * 64 + lane];
#pragma unroll
      for (int i = 0; i < 8; i++) {
        float a = bcast(hr[i], k);
        acc[i][0] += a * w0; acc[i][1] += a * w1;
        acc[i][2] += a * w2; acc[i][3] += a * w3;
      }
    }
#pragma unroll
    for (int i = 0; i < 8; i++) {
      int n = n0 + i;
      float esv = tanhf(2.f * acc[i][0]);
#pragma unroll
      for (int r = 0; r < 3; r++) {
        float hpv = acc[i][1 + r];
        int idxrn = r * N_NODES + n;
        // pack 2 bf16 channels per uint (even lane writes pair)
        uint hb = bf16r(hpv);
        uint hbp = __shfl_xor(hb, 1);
        if (!(lane & 1)) pck[(size_t)idxrn * 32 + (lane >> 1)] = (hbp << 16) | hb;
        float cs = hpv * wa0[r] + esv * wa2[r];
        float cd = hpv * wa1[r];
#pragma unroll
        for (int m = 1; m < 16; m <<= 1) {
          cs += __shfl_xor(cs, m);
          cd += __shfl_xor(cd, m);
        }
        float qv = esv * bq[r];
#pragma unroll
        for (int m = 1; m < 64; m <<= 1) qv += __shfl_xor(qv, m);
        if (k16 == 0) {
          asrc[(size_t)idxrn * 4 + hgrp] = cs + ab[r];
          adst[(size_t)idxrn * 4 + hgrp] = cd;
        }
        if (lane == 0) q[idxrn] = qv;
      }
    }
  }
}

// ---------------- fused: per-dst softmax-aggregate + gate + final linear ----------------
// wave: 4 nodes; edge loop processes 4 edges/step (16 lanes x uint2 per 128B row)
// No software pipeline; slots clamped to [beg, end-1] — no cross-segment reads.
__global__ __launch_bounds__(512, 8) void k_fused(
    const uint* __restrict__ pck, const float* __restrict__ asrc,
    const float* __restrict__ adst, const float* __restrict__ q,
    const int* __restrict__ P, const int* __restrict__ ssrc,
    const float* __restrict__ beta, const float* __restrict__ lin_w,
    const float* __restrict__ lin_b, float* __restrict__ out) {
  __shared__ uint sU[64 * 98];  // 25088 B, bf16-packed lin_w^T
  int tid = threadIdx.x;
  for (int idx = tid; idx < 96 * 64; idx += 512) {
    int c = idx & 63, jp = idx >> 6;
    float w0 = lin_w[(2 * jp) * 64 + c];
    float w1 = lin_w[(2 * jp + 1) * 64 + c];
    sU[c * 98 + jp] = (bf16r(w1) << 16) | bf16r(w0);
  }
  __syncthreads();
  int lane = tid & 63, wid = tid >> 6;
  int g = blockIdx.x * 8 + wid;  // 4 nodes per wave
  int k = lane & 15;             // channel-quad index (channels 4k..4k+3)
  int grp = lane >> 4;           // edge subgroup 0..3
  int head = k >> 2;
  float y0 = lin_b[lane];
  float y[4] = {y0, y0, y0, y0};
#pragma unroll
  for (int r = 0; r < 3; r++) {
    int rbase = r * N_NODES;
    float4 b1v = *reinterpret_cast<const float4*>(&beta[r * 128 + 64 + 4 * k]);
    float4 hr[4];
    for (int i = 0; i < 4; i++) {
      int idxrn = rbase + g * 4 + i;
      int beg = P[idxrn];
      int end = (idxrn + 1 < RN) ? P[idxrn + 1] : RE;
      float adh = adst[(size_t)idxrn * 4 + head];
      uint2 selfpv = *reinterpret_cast<const uint2*>(&pck[(size_t)idxrn * 32 + 2 * k]);
      float4 oacc = {0.f, 0.f, 0.f, 0.f};
      float dsum = 0.f, eq = 0.f;
#pragma unroll 2
      for (int e0 = beg; e0 < end; e0 += 4) {
        int slot = e0 + grp;
        bool ok = slot < end;
        int sl = ok ? slot : (end - 1);
        int rs = rbase + ssrc[sl];
        uint2 pv = *reinterpret_cast<const uint2*>(&pck[(size_t)rs * 32 + 2 * k]);
        float av = asrc[(size_t)rs * 4 + head];
        float qv = q[rs];
        float a = av + adh;
        a = a >= 0.f ? a : 0.01f * a;
        float ex = ok ? __expf(a) : 0.f;
        oacc.x += ex * lo16(pv.x);
        oacc.y += ex * hi16(pv.x);
        oacc.z += ex * lo16(pv.y);
        oacc.w += ex * hi16(pv.y);
        dsum += ex;
        eq += ok ? qv : 0.f;
      }
      // reduce across the 4 edge subgroups
#pragma unroll
      for (int m = 16; m < 64; m <<= 1) {
        oacc.x += __shfl_xor(oacc.x, m);
        oacc.y += __shfl_xor(oacc.y, m);
        oacc.z += __shfl_xor(oacc.z, m);
        oacc.w += __shfl_xor(oacc.w, m);
        dsum += __shfl_xor(dsum, m);
        eq += __shfl_xor(eq, m);
      }
      float rinv = 1.f / fmaxf(dsum, 1e-20f);
      float4 ov = {oacc.x * rinv, oacc.y * rinv, oacc.z * rinv, oacc.w * rinv};
      float cnt = fmaxf((float)(end - beg), 1.f);
      float pb = ov.x * b1v.x + ov.y * b1v.y + ov.z * b1v.z + ov.w * b1v.w;
#pragma unroll
      for (int m = 1; m < 16; m <<= 1) pb += __shfl_xor(pb, m);
      float gc = eq / cnt + pb;
      float gt = 1.f / (1.f + __expf(-gc));
      float4 hs = {lo16(selfpv.x), hi16(selfpv.x), lo16(selfpv.y), hi16(selfpv.y)};
      hr[i].x = gt * ov.x + (1.f - gt) * hs.x;
      hr[i].y = gt * ov.y + (1.f - gt) * hs.y;
      hr[i].z = gt * ov.z + (1.f - gt) * hs.z;
      hr[i].w = gt * ov.w + (1.f - gt) * hs.w;
    }
    const uint* wrow = &sU[lane * 98 + r * 32];
#pragma unroll
    for (int k2 = 0; k2 < 16; k2++) {
      uint2 wv = *reinterpret_cast<const uint2*>(wrow + 2 * k2);
      float w0 = lo16(wv.x), w1 = hi16(wv.x), w2 = lo16(wv.y), w3 = hi16(wv.y);
#pragma unroll
      for (int i = 0; i < 4; i++) {
        y[i] += bcast(hr[i].x, k2) * w0 + bcast(hr[i].y, k2) * w1 +
                bcast(hr[i].z, k2) * w2 + bcast(hr[i].w, k2) * w3;
      }
    }
  }
#pragma unroll
  for (int i = 0; i < 4; i++) out[(size_t)(g * 4 + i) * 64 + lane] = y[i];
}

extern "C" void kernel_launch(void* const* d_in, const int* in_sizes, int n_in,
                              void* d_out, int out_size, void* d_ws, size_t ws_size,
                              hipStream_t stream) {
  const float* h = (const float*)d_in[0];
  const int* src = (const int*)d_in[1];
  const int* dst = (const int*)d_in[2];
  const float* d_w = (const float*)d_in[3];
  const float* d_b = (const float*)d_in[4];
  const float* w_w = (const float*)d_in[5];
  const float* w_b = (const float*)d_in[6];
  const float* atten_w = (const float*)d_in[7];
  const float* atten_b = (const float*)d_in[8];
  const float* beta = (const float*)d_in[9];
  const float* lin_w = (const float*)d_in[10];
  const float* lin_b = (const float*)d_in[11];
  float* out = (float*)d_out;

  uint* pck = (uint*)d_ws;                        // RN*32 uints (38.4 MB)
  float* asrc = (float*)(pck + (size_t)RN * 32);  // RN*4
  float* adst = asrc + (size_t)RN * 4;            // RN*4
  float* q = adst + (size_t)RN * 4;               // RN
  int* deg = (int*)(q + RN);                      // RN
  int* P = deg + RN;                              // RN
  int* bsums = P + RN;                            // 256
  int* boffs = bsums + 256;                       // 256
  int* rank = boffs + 256;                        // RE
  int* ssrc = rank + RE;                          // RE + 16

  int nb = (RN + 2047) / 2048;
  k_zero<<<(RN + 255) / 256, 256, 0, stream>>>(deg, RN);
  k_count<<<(RE + 255) / 256, 256, 0, stream>>>(dst, deg, rank);
  k_scan1<<<nb, 256, 0, stream>>>(deg, P, bsums);
  k_scan2<<<1, 256, 0, stream>>>(bsums, boffs, nb);
  k_scan3<<<(RN + 255) / 256, 256, 0, stream>>>(P, boffs);
  k_scatter<<<(RE + 255) / 256, 256, 0, stream>>>(src, dst, rank, P, ssrc);
  k_node<<<1024, 256, 0, stream>>>(h, d_w, d_b, w_w, w_b, atten_w, atten_b, beta,
                                   pck, asrc, adst, q);
  k_fused<<<N_NODES / 32, 512, 0, stream>>>(pck, asrc, adst, q, P, ssrc, beta,
                                            lin_w, lin_b, out);
}